// Round 1
// baseline (5877.383 us; speedup 1.0000x reference)
//
#include <hip/hip_runtime.h>
#include <cstdint>
#include <cstddef>

// ---------------- problem dims ----------------
#define TT 96
#define BB 32
#define FEATD 2048
#define IND 4096
#define NG 8192           // 4*FEAT gate columns
#define MROWS 3072        // BB*TT

typedef _Float16 half8 __attribute__((ext_vector_type(8)));
typedef _Float16 half4 __attribute__((ext_vector_type(4)));
typedef float f32x4 __attribute__((ext_vector_type(4)));

// ---------------- workspace layout (bytes) ----------------
// total ~176.5 MB
#define WS_FEAT16 0u                          // [3072][4096] f16 = 25165824
#define WS_WIH16  25165824u                   // [8192][4096] f16 = 67108864
#define WS_WHH16  92274688u                   // [8192][2048] f16 = 33554432
#define WS_PRE16  125829120u                  // [3072][8192] f16 = 50331648
#define WS_HBUF   176160768u                  // 2 x [32][2048] f16 = 262144
#define WS_DOTS   176422912u                  // [96][32][5] f32 = 61440
#define WS_BAR    176484352u                  // barrier counter

// ---------------- conversion + init ----------------
__global__ void __launch_bounds__(256) k_convert(
    const float* __restrict__ feat, const float* __restrict__ wih,
    const float* __restrict__ whh,
    _Float16* __restrict__ feat16, _Float16* __restrict__ wih16,
    _Float16* __restrict__ whh16,
    float* __restrict__ dots, unsigned* __restrict__ bar)
{
  size_t id = (size_t)blockIdx.x * blockDim.x + threadIdx.x;
  size_t stride = (size_t)gridDim.x * blockDim.x;
  for (size_t i = id; i < (size_t)MROWS * IND / 4; i += stride) {
    f32x4 v = ((const f32x4*)feat)[i];
    half4 h = { (_Float16)v[0], (_Float16)v[1], (_Float16)v[2], (_Float16)v[3] };
    ((half4*)feat16)[i] = h;
  }
  for (size_t i = id; i < (size_t)NG * IND / 4; i += stride) {
    f32x4 v = ((const f32x4*)wih)[i];
    half4 h = { (_Float16)v[0], (_Float16)v[1], (_Float16)v[2], (_Float16)v[3] };
    ((half4*)wih16)[i] = h;
  }
  for (size_t i = id; i < (size_t)NG * FEATD / 4; i += stride) {
    f32x4 v = ((const f32x4*)whh)[i];
    half4 h = { (_Float16)v[0], (_Float16)v[1], (_Float16)v[2], (_Float16)v[3] };
    ((half4*)whh16)[i] = h;
  }
  for (size_t i = id; i < (size_t)TT * BB * 5; i += stride) dots[i] = 0.f;
  if (id == 0) *bar = 0u;
}

// ---------------- async global->LDS 16B ----------------
__device__ __forceinline__ void gload16(const _Float16* g, _Float16* l) {
  __builtin_amdgcn_global_load_lds(
      (const __attribute__((address_space(1))) void*)g,
      (__attribute__((address_space(3))) void*)l, 16, 0, 0);
}

// ---------------- pre = feat16 @ W_ih^T + b_ih + b_hh (m97-style 128^2 tile) ----------------
__global__ void __launch_bounds__(256, 1) k_gemm(
    const _Float16* __restrict__ A,   // [3072][4096]
    const _Float16* __restrict__ Bw,  // [8192][4096] (B^T layout: both K-contig)
    const float* __restrict__ bih, const float* __restrict__ bhh,
    _Float16* __restrict__ C)         // [3072][8192]
{
  __shared__ __align__(16) _Float16 As[128 * 32];
  __shared__ __align__(16) _Float16 Bs[128 * 32];
  const int tid = threadIdx.x;
  const int lane = tid & 63;
  const int wave = tid >> 6;
  const int wm = wave >> 1, wn = wave & 1;
  const int mbase = blockIdx.y * 128;
  const int nbase = blockIdx.x * 128;

  f32x4 acc[4][4] = {};
  const int r0 = lane >> 2;        // row within 16-row segment
  const int kc = (lane & 3) * 8;   // k offset (halfs)
  const int rr = lane & 15;
  const int ko = (lane >> 4) * 8;

  for (int k0 = 0; k0 < IND; k0 += 32) {
    // stage 128x32 A and B tiles via global_load_lds (linear LDS, wave-uniform base)
    for (int i = 0; i < 2; ++i) {
      int seg = wave * 2 + i;
      int row = seg * 16 + r0;
      gload16(A + (size_t)(mbase + row) * IND + k0 + kc, As + seg * 512);
      gload16(Bw + (size_t)(nbase + row) * IND + k0 + kc, Bs + seg * 512);
    }
    __syncthreads();   // compiler drains vmcnt before s_barrier
    half8 af[4], bf[4];
    for (int f = 0; f < 4; ++f) {
      af[f] = *(const half8*)(As + (wm * 64 + f * 16 + rr) * 32 + ko);
      bf[f] = *(const half8*)(Bs + (wn * 64 + f * 16 + rr) * 32 + ko);
    }
    for (int fm = 0; fm < 4; ++fm)
      for (int fn = 0; fn < 4; ++fn)
        acc[fm][fn] = __builtin_amdgcn_mfma_f32_16x16x32_f16(af[fm], bf[fn], acc[fm][fn], 0, 0, 0);
    __syncthreads();
  }
  // epilogue: + (b_ih + b_hh), store f16.  C/D layout: col=lane&15, row=(lane>>4)*4+r
  for (int fn = 0; fn < 4; ++fn) {
    int n = nbase + wn * 64 + fn * 16 + (lane & 15);
    float bias = bih[n] + bhh[n];
    for (int fm = 0; fm < 4; ++fm) {
      int m0 = mbase + wm * 64 + fm * 16 + (lane >> 4) * 4;
      for (int r = 0; r < 4; ++r)
        C[(size_t)(m0 + r) * NG + n] = (_Float16)(acc[fm][fn][r] + bias);
    }
  }
}

// ---------------- persistent recurrent kernel ----------------
// 256 WGs x 512 threads, 1 WG/CU. WG owns 8 h-features -> 32 gate cols.
// LDS: W_hh slice 128KB (XOR-swizzled) + reduction slots + G + c state.
#define NWG 256
#define LDS_WHH 0
#define LDS_RED 131072
#define RED_STRIDE_F 1152          // 32*36 floats per slot
#define LDS_G   149504             // [32][33] f32
#define LDS_C   153728             // [32][8] f32
#define LDS_TOTAL 154752

__global__ void __launch_bounds__(512, 1) k_recur(
    const float* __restrict__ gumbel,                          // [95][32][2]
    const float* __restrict__ Wpred, const float* __restrict__ bpred,
    const float* __restrict__ Wutil, const float* __restrict__ butil,
    const float* __restrict__ Wuse,  const float* __restrict__ buse,
    const _Float16* __restrict__ whh16,   // [8192][2048]
    const _Float16* __restrict__ pre16,   // [3072][8192], row m = b*96+t
    _Float16* __restrict__ hbuf,          // 2 x [32][2048]
    float* __restrict__ dots,             // [96][32][5]
    unsigned* __restrict__ bar,
    float* __restrict__ out)              // pred [96][32][2] ++ util [96][32]
{
  extern __shared__ __align__(16) char smem[];
  const int tid = threadIdx.x;
  const int wg = blockIdx.x;
  const int wave = tid >> 6, lane = tid & 63;
  float* Gf  = (float*)(smem + LDS_G);
  float* Cf  = (float*)(smem + LDS_C);
  float* RED = (float*)(smem + LDS_RED);

  // ---- one-time: load W_hh slice into LDS, XOR-swizzled 16B granules ----
  // logical [c 0..31][k 0..2047]; granule g=k/8; byte = c*4096 + 16*(g ^ (c&7))
  {
    int c = tid >> 4;                                   // 32 cols, 16 thr each
    int grow = (c >> 3) * FEATD + wg * 8 + (c & 7);     // gate-major row in W_hh
    const _Float16* src = whh16 + (size_t)grow * FEATD;
    char* dst = smem + LDS_WHH + c * 4096;
    int x = c & 7;
    for (int i = 0; i < 16; ++i) {
      int g = (tid & 15) + i * 16;
      *(half8*)(dst + ((g ^ x) << 4)) = *(const half8*)(src + g * 8);
    }
  }
  for (int i = tid; i < 32 * 33; i += 512) Gf[i] = 0.f;
  for (int i = tid; i < 32 * 8;  i += 512) Cf[i] = 0.f;

  const int b_ = tid >> 3, fi_ = tid & 7;   // phase-I mapping (tid<256)
  float wp0 = 0, wp1 = 0, wu0 = 0, wq0 = 0, wq1 = 0;
  if (tid < 256) {
    int gfeat = wg * 8 + fi_;
    wp0 = Wpred[gfeat]; wp1 = Wpred[FEATD + gfeat];
    wu0 = Wutil[gfeat];
    wq0 = Wuse[gfeat];  wq1 = Wuse[FEATD + gfeat];
  }
  const float bp0 = bpred[0], bp1 = bpred[1], bu0 = butil[0];
  const float bq0 = buse[0],  bq1 = buse[1];
  float Lp0 = 0.f, Lp1 = 0.f, Lu = 0.f;   // linear head carries (WG0 lanes fi==0)
  __syncthreads();

  for (int t = 0; t < TT; ++t) {
    // ================= Phase I: gates -> c,h_new; broadcast h; head dots ======
    if (tid < 256) {
      const _Float16* pr = pre16 + ((size_t)(b_ * TT + t) * NG + wg * 8 + fi_);
      float g0 = (float)pr[0]         + Gf[b_ * 33 + fi_];
      float g1 = (float)pr[FEATD]     + Gf[b_ * 33 + fi_ + 8];
      float g2 = (float)pr[2 * FEATD] + Gf[b_ * 33 + fi_ + 16];
      float g3 = (float)pr[3 * FEATD] + Gf[b_ * 33 + fi_ + 24];
      float ig = 1.f / (1.f + __expf(-g0));
      float fg = 1.f / (1.f + __expf(-g1));
      float gg = tanhf(g2);
      float og = 1.f / (1.f + __expf(-g3));
      float cc = fg * Cf[b_ * 8 + fi_] + ig * gg;
      Cf[b_ * 8 + fi_] = cc;
      float hn = og * tanhf(cc);
      hbuf[(size_t)(t & 1) * (BB * FEATD) + b_ * FEATD + wg * 8 + fi_] = (_Float16)hn;
      // partial head dots over this WG's 8 features
      float d0 = hn * wp0, d1 = hn * wp1, d2 = hn * wu0, d3 = hn * wq0, d4 = hn * wq1;
      for (int m = 1; m < 8; m <<= 1) {
        d0 += __shfl_xor(d0, m); d1 += __shfl_xor(d1, m); d2 += __shfl_xor(d2, m);
        d3 += __shfl_xor(d3, m); d4 += __shfl_xor(d4, m);
      }
      if (fi_ == 0) {
        float* dd = dots + (size_t)(t * BB + b_) * 5;
        atomicAdd(dd + 0, d0); atomicAdd(dd + 1, d1); atomicAdd(dd + 2, d2);
        atomicAdd(dd + 3, d3); atomicAdd(dd + 4, d4);
      }
    }
    // ================= grid barrier (sense-free monotone counter) =============
    __syncthreads();                       // drains vmcnt -> stores in L2
    if (tid == 0) {
      __threadfence();                     // L2 writeback (cross-XCD release)
      __hip_atomic_fetch_add(bar, 1u, __ATOMIC_RELAXED, __HIP_MEMORY_SCOPE_AGENT);
      const unsigned target = (unsigned)(t + 1) * NWG;
      while (__hip_atomic_load(bar, __ATOMIC_RELAXED, __HIP_MEMORY_SCOPE_AGENT) < target)
        __builtin_amdgcn_s_sleep(2);
      __threadfence();                     // acquire: invalidate L1+L2
    }
    __syncthreads();

    // ================= Phase II: M = h_new @ W_hh^T (8-wave k-split) ==========
    const _Float16* hb = hbuf + (size_t)(t & 1) * (BB * FEATD);
    f32x4 acc[2][2] = {};
    {
      const int rr = lane & 15;
      const int lk = (lane >> 4) * 8;
      const int c0 = rr, c1 = 16 + rr;
      const char* wsl = smem + LDS_WHH;
      for (int s = 0; s < 8; ++s) {
        int kk = wave * 256 + s * 32 + lk;
        half8 a0 = *(const half8*)(hb + rr * FEATD + kk);
        half8 a1 = *(const half8*)(hb + (16 + rr) * FEATD + kk);
        int g = kk >> 3;
        half8 b0 = *(const half8*)(wsl + c0 * 4096 + ((g ^ (c0 & 7)) << 4));
        half8 b1 = *(const half8*)(wsl + c1 * 4096 + ((g ^ (c1 & 7)) << 4));
        acc[0][0] = __builtin_amdgcn_mfma_f32_16x16x32_f16(a0, b0, acc[0][0], 0, 0, 0);
        acc[0][1] = __builtin_amdgcn_mfma_f32_16x16x32_f16(a0, b1, acc[0][1], 0, 0, 0);
        acc[1][0] = __builtin_amdgcn_mfma_f32_16x16x32_f16(a1, b0, acc[1][0], 0, 0, 0);
        acc[1][1] = __builtin_amdgcn_mfma_f32_16x16x32_f16(a1, b1, acc[1][1], 0, 0, 0);
      }
    }
    // ---- tree reduction of 8 partials; slot layout [c][36] f32 (16B-aligned vec4) ----
    {
      const int bb0 = (lane >> 4) * 4;
      const int cc0 = lane & 15;
      if (wave >= 4) {
        float* s0 = RED + (wave - 4) * RED_STRIDE_F;
        for (int fm = 0; fm < 2; ++fm)
          for (int fn = 0; fn < 2; ++fn)
            *(f32x4*)(s0 + (fn * 16 + cc0) * 36 + fm * 16 + bb0) = acc[fm][fn];
      }
      __syncthreads();
      if (wave < 4) {
        float* s0 = RED + wave * RED_STRIDE_F;
        for (int fm = 0; fm < 2; ++fm)
          for (int fn = 0; fn < 2; ++fn)
            acc[fm][fn] += *(f32x4*)(s0 + (fn * 16 + cc0) * 36 + fm * 16 + bb0);
        if (wave >= 2)
          for (int fm = 0; fm < 2; ++fm)
            for (int fn = 0; fn < 2; ++fn)
              *(f32x4*)(s0 + (fn * 16 + cc0) * 36 + fm * 16 + bb0) = acc[fm][fn];
      }
      __syncthreads();
      if (wave < 2) {
        float* s2 = RED + (wave + 2) * RED_STRIDE_F;
        for (int fm = 0; fm < 2; ++fm)
          for (int fn = 0; fn < 2; ++fn)
            acc[fm][fn] += *(f32x4*)(s2 + (fn * 16 + cc0) * 36 + fm * 16 + bb0);
        if (wave == 1) {
          float* s3 = RED + 3 * RED_STRIDE_F;
          for (int fm = 0; fm < 2; ++fm)
            for (int fn = 0; fn < 2; ++fn)
              *(f32x4*)(s3 + (fn * 16 + cc0) * 36 + fm * 16 + bb0) = acc[fm][fn];
        }
      }
      __syncthreads();
      if (wave == 0) {
        float* s3 = RED + 3 * RED_STRIDE_F;
        for (int fm = 0; fm < 2; ++fm)
          for (int fn = 0; fn < 2; ++fn) {
            acc[fm][fn] += *(f32x4*)(s3 + (fn * 16 + cc0) * 36 + fm * 16 + bb0);
            *(f32x4*)(RED + (fn * 16 + cc0) * 36 + fm * 16 + bb0) = acc[fm][fn];  // slot0 = M
          }
      }
      __syncthreads();
    }
    // ================= gate mix scalars + G update + outputs ==================
    if (tid < 256) {
      float ga = 0.f, gb = 1.f;
      if (t > 0) {
        const float* dd = dots + (size_t)(t * BB + b_) * 5;
        float u0 = gumbel[(size_t)(t - 1) * 64 + b_ * 2 + 0];
        float u1 = gumbel[(size_t)(t - 1) * 64 + b_ * 2 + 1];
        float n0 = -logf(-logf(u0 + 1e-10f) + 1e-10f);
        float n1 = -logf(-logf(u1 + 1e-10f) + 1e-10f);
        float l0 = dd[3] + bq0 + n0;
        float l1 = dd[4] + bq1 + n1;
        float mx = fmaxf(l0, l1);
        float e0 = __expf(l0 - mx), e1 = __expf(l1 - mx);
        float inv = 1.f / (e0 + e1);
        ga = e0 * inv; gb = e1 * inv;
      }
      for (int j = 0; j < 4; ++j) {
        int c = fi_ + 8 * j;
        Gf[b_ * 33 + c] = ga * Gf[b_ * 33 + c] + gb * RED[c * 36 + b_];
      }
      if (wg == 0 && fi_ == 0) {
        const float* dd = dots + (size_t)(t * BB + b_) * 5;
        Lp0 = ga * Lp0 + gb * dd[0];
        Lp1 = ga * Lp1 + gb * dd[1];
        Lu  = ga * Lu  + gb * dd[2];
        out[(t * BB + b_) * 2 + 0] = Lp0 + bp0;
        out[(t * BB + b_) * 2 + 1] = Lp1 + bp1;
        out[TT * BB * 2 + t * BB + b_] = Lu + bu0;
      }
    }
    // no extra sync: G/c re-read only by same threads; RED rewritten after next grid barrier
  }
}

// ---------------- host launcher ----------------
extern "C" void kernel_launch(void* const* d_in, const int* in_sizes, int n_in,
                              void* d_out, int out_size, void* d_ws, size_t ws_size,
                              hipStream_t stream) {
  const float* feat  = (const float*)d_in[0];
  const float* gumb  = (const float*)d_in[1];
  const float* Wih   = (const float*)d_in[2];
  const float* bih   = (const float*)d_in[3];
  const float* Whh   = (const float*)d_in[4];
  const float* bhh   = (const float*)d_in[5];
  const float* Wpred = (const float*)d_in[6];
  const float* bpred = (const float*)d_in[7];
  const float* Wutil = (const float*)d_in[8];
  const float* butil = (const float*)d_in[9];
  const float* Wuse  = (const float*)d_in[10];
  const float* buse  = (const float*)d_in[11];

  char* ws = (char*)d_ws;
  _Float16* feat16 = (_Float16*)(ws + WS_FEAT16);
  _Float16* wih16  = (_Float16*)(ws + WS_WIH16);
  _Float16* whh16  = (_Float16*)(ws + WS_WHH16);
  _Float16* pre16  = (_Float16*)(ws + WS_PRE16);
  _Float16* hbufp  = (_Float16*)(ws + WS_HBUF);
  float*    dotsp  = (float*)(ws + WS_DOTS);
  unsigned* barp   = (unsigned*)(ws + WS_BAR);

  (void)in_sizes; (void)n_in; (void)out_size; (void)ws_size;

  hipFuncSetAttribute((const void*)k_recur,
                      hipFuncAttributeMaxDynamicSharedMemorySize, LDS_TOTAL);

  k_convert<<<2048, 256, 0, stream>>>(feat, Wih, Whh, feat16, wih16, whh16, dotsp, barp);
  dim3 g2(NG / 128, MROWS / 128);
  k_gemm<<<g2, 256, 0, stream>>>(feat16, wih16, bih, bhh, pre16);
  k_recur<<<NWG, 512, LDS_TOTAL, stream>>>(gumb, Wpred, bpred, Wutil, butil, Wuse, buse,
                                           whh16, pre16, hbufp, dotsp, barp, (float*)d_out);
}

// Round 2
// 1157.881 us; speedup vs baseline: 5.0760x; 5.0760x over previous
//
#include <hip/hip_runtime.h>
#include <cstdint>
#include <cstddef>

// ---------------- problem dims ----------------
#define TT 96
#define BB 32
#define FEATD 2048
#define IND 4096
#define NG 8192           // 4*FEAT gate columns
#define MROWS 3072        // BB*TT

typedef _Float16 half8 __attribute__((ext_vector_type(8)));
typedef _Float16 half4 __attribute__((ext_vector_type(4)));
typedef float f32x4 __attribute__((ext_vector_type(4)));

// ---------------- workspace layout (bytes) ----------------
// hbuf (96 x [32][2048] f16 = 12.58 MB) OVERLAYS feat16 (dead after k_gemm).
#define WS_FEAT16 0u                          // [3072][4096] f16 = 25165824
#define WS_HBUF   0u                          // 96 x [32][2048] f16 = 12582912 (overlay)
#define WS_WIH16  25165824u                   // [8192][4096] f16 = 67108864
#define WS_WHH16  92274688u                   // [8192][2048] f16 = 33554432
#define WS_PRE16  125829120u                  // [3072][8192] f16 = 50331648
#define WS_GAB    176160768u                  // [96][32][2] f32 = 24576
#define WS_HD     176185344u                  // [96][32][3] f32 = 36864
#define WS_BAR    176222208u                  // 33 x 256B barrier words = 8448

#define NWG 256
#define BAR_WORDS (33 * 64)   // u32 words, 64-word (256B) stride per counter

// ---------------- conversion + init ----------------
__global__ void __launch_bounds__(256) k_convert(
    const float* __restrict__ feat, const float* __restrict__ wih,
    const float* __restrict__ whh,
    _Float16* __restrict__ feat16, _Float16* __restrict__ wih16,
    _Float16* __restrict__ whh16, unsigned* __restrict__ barr)
{
  size_t id = (size_t)blockIdx.x * blockDim.x + threadIdx.x;
  size_t stride = (size_t)gridDim.x * blockDim.x;
  for (size_t i = id; i < (size_t)MROWS * IND / 4; i += stride) {
    f32x4 v = ((const f32x4*)feat)[i];
    half4 h = { (_Float16)v[0], (_Float16)v[1], (_Float16)v[2], (_Float16)v[3] };
    ((half4*)feat16)[i] = h;
  }
  for (size_t i = id; i < (size_t)NG * IND / 4; i += stride) {
    f32x4 v = ((const f32x4*)wih)[i];
    half4 h = { (_Float16)v[0], (_Float16)v[1], (_Float16)v[2], (_Float16)v[3] };
    ((half4*)wih16)[i] = h;
  }
  for (size_t i = id; i < (size_t)NG * FEATD / 4; i += stride) {
    f32x4 v = ((const f32x4*)whh)[i];
    half4 h = { (_Float16)v[0], (_Float16)v[1], (_Float16)v[2], (_Float16)v[3] };
    ((half4*)whh16)[i] = h;
  }
  for (size_t i = id; i < BAR_WORDS; i += stride) barr[i] = 0u;
}

// ---------------- async global->LDS 16B ----------------
__device__ __forceinline__ void gload16(const _Float16* g, _Float16* l) {
  __builtin_amdgcn_global_load_lds(
      (const __attribute__((address_space(1))) void*)g,
      (__attribute__((address_space(3))) void*)l, 16, 0, 0);
}

// ---------------- pre = feat16 @ W_ih^T + b_ih + b_hh ----------------
__global__ void __launch_bounds__(256, 1) k_gemm(
    const _Float16* __restrict__ A,   // [3072][4096]
    const _Float16* __restrict__ Bw,  // [8192][4096]
    const float* __restrict__ bih, const float* __restrict__ bhh,
    _Float16* __restrict__ C)         // [3072][8192]
{
  __shared__ __align__(16) _Float16 As[128 * 32];
  __shared__ __align__(16) _Float16 Bs[128 * 32];
  const int tid = threadIdx.x;
  const int lane = tid & 63;
  const int wave = tid >> 6;
  const int wm = wave >> 1, wn = wave & 1;
  const int mbase = blockIdx.y * 128;
  const int nbase = blockIdx.x * 128;

  f32x4 acc[4][4] = {};
  const int r0 = lane >> 2;
  const int kc = (lane & 3) * 8;
  const int rr = lane & 15;
  const int ko = (lane >> 4) * 8;

  for (int k0 = 0; k0 < IND; k0 += 32) {
    for (int i = 0; i < 2; ++i) {
      int seg = wave * 2 + i;
      int row = seg * 16 + r0;
      gload16(A + (size_t)(mbase + row) * IND + k0 + kc, As + seg * 512);
      gload16(Bw + (size_t)(nbase + row) * IND + k0 + kc, Bs + seg * 512);
    }
    __syncthreads();
    half8 af[4], bf[4];
    for (int f = 0; f < 4; ++f) {
      af[f] = *(const half8*)(As + (wm * 64 + f * 16 + rr) * 32 + ko);
      bf[f] = *(const half8*)(Bs + (wn * 64 + f * 16 + rr) * 32 + ko);
    }
    for (int fm = 0; fm < 4; ++fm)
      for (int fn = 0; fn < 4; ++fn)
        acc[fm][fn] = __builtin_amdgcn_mfma_f32_16x16x32_f16(af[fm], bf[fn], acc[fm][fn], 0, 0, 0);
    __syncthreads();
  }
  for (int fn = 0; fn < 4; ++fn) {
    int n = nbase + wn * 64 + fn * 16 + (lane & 15);
    float bias = bih[n] + bhh[n];
    for (int fm = 0; fm < 4; ++fm) {
      int m0 = mbase + wm * 64 + fm * 16 + (lane >> 4) * 4;
      for (int r = 0; r < 4; ++r)
        C[(size_t)(m0 + r) * NG + n] = (_Float16)(acc[fm][fn][r] + bias);
    }
  }
}

// ---------------- persistent recurrent kernel ----------------
#define LDS_WHH 0
#define LDS_RED 131072
#define RED_STRIDE_F 1152          // 32*36 floats per slot; cols use [0..31], pads [32..35]
#define LDS_G   149504             // [32][33] f32
#define LDS_C   153728             // [32][8] f32
#define LDS_TOTAL 154752

__global__ void __launch_bounds__(512, 1) k_recur(
    const float* __restrict__ gumbel,     // [95][32][2]
    const float* __restrict__ Wuse, const float* __restrict__ buse,
    const _Float16* __restrict__ whh16,   // [8192][2048]
    const _Float16* __restrict__ pre16,   // [3072][8192], row m = b*96+t
    _Float16* __restrict__ hbuf,          // 96 x [32][2048]  (h_new per step)
    float* __restrict__ gab,              // [96][32][2] ga/gb
    unsigned* __restrict__ barr)          // 2-level barrier words
{
  extern __shared__ __align__(16) char smem[];
  const int tid = threadIdx.x;
  const int wg = blockIdx.x;
  const int wave = tid >> 6, lane = tid & 63;
  float* Gf  = (float*)(smem + LDS_G);
  float* Cf  = (float*)(smem + LDS_C);
  float* RED = (float*)(smem + LDS_RED);

  // ---- one-time: W_hh slice into LDS, XOR-swizzled 16B granules ----
  {
    int c = tid >> 4;
    int grow = (c >> 3) * FEATD + wg * 8 + (c & 7);
    const _Float16* src = whh16 + (size_t)grow * FEATD;
    char* dst = smem + LDS_WHH + c * 4096;
    int x = c & 7;
    for (int i = 0; i < 16; ++i) {
      int g = (tid & 15) + i * 16;
      *(half8*)(dst + ((g ^ x) << 4)) = *(const half8*)(src + g * 8);
    }
  }
  for (int i = tid; i < 32 * 33; i += 512) Gf[i] = 0.f;
  for (int i = tid; i < 32 * 8;  i += 512) Cf[i] = 0.f;

  // ---- use-head weights for this lane's k-slices, in registers (f16) ----
  const int rr = lane & 15;
  const int lk = (lane >> 4) * 8;
  half8 uq0[8], uq1[8];
#pragma unroll
  for (int s = 0; s < 8; ++s) {
    int kk = wave * 256 + s * 32 + lk;
#pragma unroll
    for (int e = 0; e < 8; ++e) {
      uq0[s][e] = (_Float16)Wuse[kk + e];
      uq1[s][e] = (_Float16)Wuse[FEATD + kk + e];
    }
  }

  const int b_ = tid >> 3, fi_ = tid & 7;   // phase-I mapping (tid<256)
  const float bq0 = buse[0], bq1 = buse[1];

  // prefetch pre16 for t=0 (+ gumbel regs)
  const _Float16* prbase = pre16 + ((size_t)b_ * TT) * NG + wg * 8 + fi_;
  _Float16 pf0 = 0, pf1 = 0, pf2 = 0, pf3 = 0;
  float gum0 = 0.f, gum1 = 0.f;
  if (tid < 256) {
    pf0 = prbase[0]; pf1 = prbase[FEATD]; pf2 = prbase[2 * FEATD]; pf3 = prbase[3 * FEATD];
  }
  __syncthreads();

  for (int t = 0; t < TT; ++t) {
    // ============ Phase I: gates -> c,h_new; agent-store h ============
    if (tid < 256) {
      float g0 = (float)pf0 + Gf[b_ * 33 + fi_];
      float g1 = (float)pf1 + Gf[b_ * 33 + fi_ + 8];
      float g2 = (float)pf2 + Gf[b_ * 33 + fi_ + 16];
      float g3 = (float)pf3 + Gf[b_ * 33 + fi_ + 24];
      float ig = 1.f / (1.f + __expf(-g0));
      float fg = 1.f / (1.f + __expf(-g1));
      float gg = tanhf(g2);
      float og = 1.f / (1.f + __expf(-g3));
      float cc = fg * Cf[b_ * 8 + fi_] + ig * gg;
      Cf[b_ * 8 + fi_] = cc;
      float hn = og * tanhf(cc);
      float hn_o = __shfl_xor(hn, 1);
      if ((fi_ & 1) == 0) {
        union { _Float16 h[2]; unsigned u; } pk;
        pk.h[0] = (_Float16)hn; pk.h[1] = (_Float16)hn_o;
        unsigned* dst = (unsigned*)(hbuf + (size_t)t * (BB * FEATD) + b_ * FEATD + wg * 8 + fi_);
        __hip_atomic_store(dst, pk.u, __ATOMIC_RELAXED, __HIP_MEMORY_SCOPE_AGENT);
      }
    }
    // ============ grid barrier: 2-level, monotone counters ============
    __syncthreads();                       // drains vmcnt: h-stores complete at IF
    if (tid == 0) {
      const unsigned tgt = (unsigned)(t + 1);
      const int g = wg >> 4;
      __hip_atomic_fetch_add(&barr[g * 64], 1u, __ATOMIC_RELAXED, __HIP_MEMORY_SCOPE_AGENT);
      if ((wg & 15) == 0) {
        while (__hip_atomic_load(&barr[g * 64], __ATOMIC_RELAXED, __HIP_MEMORY_SCOPE_AGENT) < 16u * tgt)
          __builtin_amdgcn_s_sleep(1);
        __hip_atomic_fetch_add(&barr[16 * 64], 1u, __ATOMIC_RELAXED, __HIP_MEMORY_SCOPE_AGENT);
        while (__hip_atomic_load(&barr[16 * 64], __ATOMIC_RELAXED, __HIP_MEMORY_SCOPE_AGENT) < 16u * tgt)
          __builtin_amdgcn_s_sleep(1);
        __hip_atomic_store(&barr[(17 + g) * 64], tgt, __ATOMIC_RELAXED, __HIP_MEMORY_SCOPE_AGENT);
      } else {
        while (__hip_atomic_load(&barr[(17 + g) * 64], __ATOMIC_RELAXED, __HIP_MEMORY_SCOPE_AGENT) < tgt)
          __builtin_amdgcn_s_sleep(1);
      }
    }
    __syncthreads();

    // ============ Phase II: M = h_new @ W_hh^T  + use-head dots ============
    const _Float16* hb = hbuf + (size_t)t * (BB * FEATD);
    f32x4 acc[2][2] = {};
    float q0a = 0.f, q1a = 0.f, q0b = 0.f, q1b = 0.f;
    {
      const int c0 = rr, c1 = 16 + rr;
      const char* wsl = smem + LDS_WHH;
#pragma unroll
      for (int s = 0; s < 8; ++s) {
        int kk = wave * 256 + s * 32 + lk;
        half8 a0 = *(const half8*)(hb + rr * FEATD + kk);
        half8 a1 = *(const half8*)(hb + (16 + rr) * FEATD + kk);
        int g = kk >> 3;
        half8 b0 = *(const half8*)(wsl + c0 * 4096 + ((g ^ (c0 & 7)) << 4));
        half8 b1 = *(const half8*)(wsl + c1 * 4096 + ((g ^ (c1 & 7)) << 4));
        acc[0][0] = __builtin_amdgcn_mfma_f32_16x16x32_f16(a0, b0, acc[0][0], 0, 0, 0);
        acc[0][1] = __builtin_amdgcn_mfma_f32_16x16x32_f16(a0, b1, acc[0][1], 0, 0, 0);
        acc[1][0] = __builtin_amdgcn_mfma_f32_16x16x32_f16(a1, b0, acc[1][0], 0, 0, 0);
        acc[1][1] = __builtin_amdgcn_mfma_f32_16x16x32_f16(a1, b1, acc[1][1], 0, 0, 0);
#pragma unroll
        for (int e = 0; e < 8; ++e) {
          float xa = (float)a0[e], xb = (float)a1[e];
          q0a += xa * (float)uq0[s][e]; q1a += xa * (float)uq1[s][e];
          q0b += xb * (float)uq0[s][e]; q1b += xb * (float)uq1[s][e];
        }
      }
    }
    // use-head: reduce across the 4 k-groups (lane bits 4,5)
    q0a += __shfl_xor(q0a, 16); q0a += __shfl_xor(q0a, 32);
    q1a += __shfl_xor(q1a, 16); q1a += __shfl_xor(q1a, 32);
    q0b += __shfl_xor(q0b, 16); q0b += __shfl_xor(q0b, 32);
    q1b += __shfl_xor(q1b, 16); q1b += __shfl_xor(q1b, 32);
    if (lane < 16) {   // stash per-wave partials in RED slot padding floats [32..35]
      float* pads = RED + (wave & 3) * RED_STRIDE_F + 32 + (wave >> 2) * 2;
      pads[rr * 36 + 0] = q0a; pads[rr * 36 + 1] = q1a;
      pads[(16 + rr) * 36 + 0] = q0b; pads[(16 + rr) * 36 + 1] = q1b;
    }
    // ---- tree reduction of 8 MFMA partials ----
    {
      const int bb0 = (lane >> 4) * 4;
      const int cc0 = lane & 15;
      if (wave >= 4) {
        float* s0 = RED + (wave - 4) * RED_STRIDE_F;
        for (int fm = 0; fm < 2; ++fm)
          for (int fn = 0; fn < 2; ++fn)
            *(f32x4*)(s0 + (fn * 16 + cc0) * 36 + fm * 16 + bb0) = acc[fm][fn];
      }
      __syncthreads();
      if (wave < 4) {
        float* s0 = RED + wave * RED_STRIDE_F;
        for (int fm = 0; fm < 2; ++fm)
          for (int fn = 0; fn < 2; ++fn)
            acc[fm][fn] += *(f32x4*)(s0 + (fn * 16 + cc0) * 36 + fm * 16 + bb0);
        if (wave >= 2)
          for (int fm = 0; fm < 2; ++fm)
            for (int fn = 0; fn < 2; ++fn)
              *(f32x4*)(s0 + (fn * 16 + cc0) * 36 + fm * 16 + bb0) = acc[fm][fn];
      }
      __syncthreads();
      if (wave < 2) {
        float* s2 = RED + (wave + 2) * RED_STRIDE_F;
        for (int fm = 0; fm < 2; ++fm)
          for (int fn = 0; fn < 2; ++fn)
            acc[fm][fn] += *(f32x4*)(s2 + (fn * 16 + cc0) * 36 + fm * 16 + bb0);
        if (wave == 1) {
          float* s3 = RED + 3 * RED_STRIDE_F;
          for (int fm = 0; fm < 2; ++fm)
            for (int fn = 0; fn < 2; ++fn)
              *(f32x4*)(s3 + (fn * 16 + cc0) * 36 + fm * 16 + bb0) = acc[fm][fn];
        }
      }
      __syncthreads();
      if (wave == 0) {
        float* s3 = RED + 3 * RED_STRIDE_F;
        for (int fm = 0; fm < 2; ++fm)
          for (int fn = 0; fn < 2; ++fn) {
            acc[fm][fn] += *(f32x4*)(s3 + (fn * 16 + cc0) * 36 + fm * 16 + bb0);
            *(f32x4*)(RED + (fn * 16 + cc0) * 36 + fm * 16 + bb0) = acc[fm][fn];
          }
      }
      __syncthreads();
    }
    // ============ gate mix + G update + prefetch next step ============
    if (tid < 256) {
      float ga = 0.f, gb = 1.f;
      if (t > 0) {
        float q0 = bq0, q1 = bq1;
#pragma unroll
        for (int s2 = 0; s2 < 4; ++s2) {
          const float* pp = RED + s2 * RED_STRIDE_F + b_ * 36 + 32;
          q0 += pp[0] + pp[2]; q1 += pp[1] + pp[3];
        }
        float n0 = -logf(-logf(gum0 + 1e-10f) + 1e-10f);
        float n1 = -logf(-logf(gum1 + 1e-10f) + 1e-10f);
        float l0 = q0 + n0;
        float l1 = q1 + n1;
        float mx = fmaxf(l0, l1);
        float e0 = __expf(l0 - mx), e1 = __expf(l1 - mx);
        float inv = 1.f / (e0 + e1);
        ga = e0 * inv; gb = e1 * inv;
        if (wg == 0 && fi_ == 0) {
          gab[(t * BB + b_) * 2 + 0] = ga;
          gab[(t * BB + b_) * 2 + 1] = gb;
        }
      }
#pragma unroll
      for (int j = 0; j < 4; ++j) {
        int c = fi_ + 8 * j;
        Gf[b_ * 33 + c] = ga * Gf[b_ * 33 + c] + gb * RED[c * 36 + b_];
      }
      // prefetch next step's pre16 + gumbel (hides L3 latency under barrier)
      if (t + 1 < TT) {
        const _Float16* p = prbase + (size_t)(t + 1) * NG;
        pf0 = p[0]; pf1 = p[FEATD]; pf2 = p[2 * FEATD]; pf3 = p[3 * FEATD];
        gum0 = gumbel[(size_t)t * 64 + b_ * 2 + 0];
        gum1 = gumbel[(size_t)t * 64 + b_ * 2 + 1];
      }
    }
    // RED rewritten only after next grid barrier; Gf/Cf same-thread -> no extra sync
  }
}

// ---------------- post: head dots per (t,b) ----------------
__global__ void __launch_bounds__(256) k_heads(
    const _Float16* __restrict__ hbuf,   // 96 x [32][2048]
    const float* __restrict__ Wpred, const float* __restrict__ Wutil,
    float* __restrict__ hd)              // [96][32][3]
{
  const int t = blockIdx.x;
  const int tid = threadIdx.x;
  const int b = tid >> 3, fi = tid & 7;
  const _Float16* h = hbuf + ((size_t)t * BB + b) * FEATD;
  float d0 = 0.f, d1 = 0.f, d2 = 0.f;
  for (int j = 0; j < 32; ++j) {
    int k = fi * 8 + j * 64;
    half8 v = *(const half8*)(h + k);
#pragma unroll
    for (int e = 0; e < 8; ++e) {
      float x = (float)v[e];
      d0 += x * Wpred[k + e];
      d1 += x * Wpred[FEATD + k + e];
      d2 += x * Wutil[k + e];
    }
  }
  for (int m = 1; m < 8; m <<= 1) {
    d0 += __shfl_xor(d0, m); d1 += __shfl_xor(d1, m); d2 += __shfl_xor(d2, m);
  }
  if (fi == 0) {
    float* o = hd + ((size_t)t * BB + b) * 3;
    o[0] = d0; o[1] = d1; o[2] = d2;
  }
}

// ---------------- post: linear scan over t + output ----------------
__global__ void __launch_bounds__(64) k_scan(
    const float* __restrict__ hd,    // [96][32][3]
    const float* __restrict__ gab,   // [96][32][2]
    const float* __restrict__ bpred, const float* __restrict__ butil,
    float* __restrict__ out)         // pred [96][32][2] ++ util [96][32]
{
  const int b = threadIdx.x;
  if (b >= BB) return;
  const float bp0 = bpred[0], bp1 = bpred[1], bu0 = butil[0];
  float L0 = hd[b * 3 + 0], L1 = hd[b * 3 + 1], L2 = hd[b * 3 + 2];
  out[b * 2 + 0] = L0 + bp0;
  out[b * 2 + 1] = L1 + bp1;
  out[TT * BB * 2 + b] = L2 + bu0;
  for (int t = 1; t < TT; ++t) {
    float ga = gab[(t * BB + b) * 2 + 0];
    float gb = gab[(t * BB + b) * 2 + 1];
    const float* d = hd + ((size_t)t * BB + b) * 3;
    L0 = ga * L0 + gb * d[0];
    L1 = ga * L1 + gb * d[1];
    L2 = ga * L2 + gb * d[2];
    out[(t * BB + b) * 2 + 0] = L0 + bp0;
    out[(t * BB + b) * 2 + 1] = L1 + bp1;
    out[TT * BB * 2 + t * BB + b] = L2 + bu0;
  }
}

// ---------------- host launcher ----------------
extern "C" void kernel_launch(void* const* d_in, const int* in_sizes, int n_in,
                              void* d_out, int out_size, void* d_ws, size_t ws_size,
                              hipStream_t stream) {
  const float* feat  = (const float*)d_in[0];
  const float* gumb  = (const float*)d_in[1];
  const float* Wih   = (const float*)d_in[2];
  const float* bih   = (const float*)d_in[3];
  const float* Whh   = (const float*)d_in[4];
  const float* bhh   = (const float*)d_in[5];
  const float* Wpred = (const float*)d_in[6];
  const float* bpred = (const float*)d_in[7];
  const float* Wutil = (const float*)d_in[8];
  const float* butil = (const float*)d_in[9];
  const float* Wuse  = (const float*)d_in[10];
  const float* buse  = (const float*)d_in[11];

  char* ws = (char*)d_ws;
  _Float16* feat16 = (_Float16*)(ws + WS_FEAT16);
  _Float16* hbufp  = (_Float16*)(ws + WS_HBUF);     // overlays feat16
  _Float16* wih16  = (_Float16*)(ws + WS_WIH16);
  _Float16* whh16  = (_Float16*)(ws + WS_WHH16);
  _Float16* pre16  = (_Float16*)(ws + WS_PRE16);
  float*    gabp   = (float*)(ws + WS_GAB);
  float*    hdp    = (float*)(ws + WS_HD);
  unsigned* barp   = (unsigned*)(ws + WS_BAR);

  (void)in_sizes; (void)n_in; (void)out_size; (void)ws_size;

  hipFuncSetAttribute((const void*)k_recur,
                      hipFuncAttributeMaxDynamicSharedMemorySize, LDS_TOTAL);

  k_convert<<<2048, 256, 0, stream>>>(feat, Wih, Whh, feat16, wih16, whh16, barp);
  dim3 g2(NG / 128, MROWS / 128);
  k_gemm<<<g2, 256, 0, stream>>>(feat16, wih16, bih, bhh, pre16);
  k_recur<<<NWG, 512, LDS_TOTAL, stream>>>(gumb, Wuse, buse, whh16, pre16,
                                           hbufp, gabp, barp);
  k_heads<<<TT, 256, 0, stream>>>(hbufp, Wpred, Wutil, hdp);
  k_scan<<<1, 64, 0, stream>>>(hdp, gabp, bpred, butil, (float*)d_out);
}